// Round 6
// baseline (668.475 us; speedup 1.0000x reference)
//
#include <hip/hip_runtime.h>
#include <cstdint>
#include <cstddef>

typedef __bf16 bf16x8 __attribute__((ext_vector_type(8)));
typedef float f32x4 __attribute__((ext_vector_type(4)));
typedef float f32x16 __attribute__((ext_vector_type(16)));
typedef unsigned short ushort8 __attribute__((ext_vector_type(8)));
typedef unsigned u32x2 __attribute__((ext_vector_type(2)));
typedef float f4 __attribute__((ext_vector_type(4)));

__device__ __forceinline__ unsigned short f2bf(float f) {
    __bf16 b = (__bf16)f;
    return *(unsigned short*)&b;
}
__device__ __forceinline__ unsigned pk2bf(float a, float b) {
    __bf16 x = (__bf16)a, y = (__bf16)b;
    unsigned short ux = *(unsigned short*)&x, uy = *(unsigned short*)&y;
    return (unsigned)ux | ((unsigned)uy << 16);
}
__device__ __forceinline__ float bf2f(unsigned short u) {
    union { unsigned u; float f; } v; v.u = ((unsigned)u) << 16; return v.f;
}

#if __has_builtin(__builtin_amdgcn_exp2f)
#define EXP2(x) __builtin_amdgcn_exp2f(x)
#else
#define EXP2(x) exp2f(x)
#endif

// exchange high 32 lanes of x with low 32 lanes of y (v_permlane32_swap_b32)
__device__ __forceinline__ void pl32swap(unsigned& x, unsigned& y) {
#if __has_builtin(__builtin_amdgcn_permlane32_swap)
    auto r = __builtin_amdgcn_permlane32_swap(x, y, false, false);
    x = r[0]; y = r[1];
#else
    unsigned xs = (unsigned)__shfl_xor((int)x, 32, 64);
    unsigned ys = (unsigned)__shfl_xor((int)y, 32, 64);
    bool lo = ((threadIdx.x & 63) < 32);
    unsigned nx = lo ? x : ys;
    unsigned ny = lo ? xs : y;
    x = nx; y = ny;
#endif
}

#define GLL(g, l) __builtin_amdgcn_global_load_lds( \
    (__attribute__((address_space(1))) void*)(g), \
    (__attribute__((address_space(3))) void*)(l), 16, 0, 0)

#define CS 0.18033688011112042f   /* 0.125 * log2(e) */

// ---------------------------------------------------------------------------
// 1. Convert the four 512x512 fp32 weight matrices to bf16 (concatenated).
// ---------------------------------------------------------------------------
__global__ __launch_bounds__(256) void convert_w(
    const float* __restrict__ wq, const float* __restrict__ wk,
    const float* __restrict__ wv, const float* __restrict__ wo,
    unsigned short* __restrict__ out)
{
    int i = blockIdx.x * 256 + threadIdx.x;
    const float* src = (i < 262144) ? wq : (i < 524288) ? wk : (i < 786432) ? wv : wo;
    out[i] = f2bf(src[i & 262143]);
}

// ---------------------------------------------------------------------------
// 2a. GroupNorm stats: grid (4 quarters, 64 b*g); partials -> part[(bg*4+q)*2]
// ---------------------------------------------------------------------------
__global__ __launch_bounds__(256) void gn_stats(
    const float* __restrict__ x, float* __restrict__ part)
{
    const int q = blockIdx.x, bg = blockIdx.y;
    const f4* xv = (const f4*)(x + (size_t)bg * 65536 + q * 16384);
    float s = 0.f, sq = 0.f;
    for (int i = threadIdx.x; i < 4096; i += 256) {
        f4 v = xv[i];
        s  += v.x + v.y + v.z + v.w;
        sq += v.x * v.x + v.y * v.y + v.z * v.z + v.w * v.w;
    }
    #pragma unroll
    for (int off = 32; off > 0; off >>= 1) {
        s  += __shfl_xor(s, off, 64);
        sq += __shfl_xor(sq, off, 64);
    }
    __shared__ float red[8];
    const int w = threadIdx.x >> 6, lane = threadIdx.x & 63;
    if (lane == 0) { red[w] = s; red[4 + w] = sq; }
    __syncthreads();
    if (threadIdx.x == 0) {
        part[(bg * 4 + q) * 2]     = red[0] + red[1] + red[2] + red[3];
        part[(bg * 4 + q) * 2 + 1] = red[4] + red[5] + red[6] + red[7];
    }
}

// ---------------------------------------------------------------------------
// 2b. GroupNorm apply -> h bf16 in [B*N, C] layout.
// ---------------------------------------------------------------------------
__global__ __launch_bounds__(256) void gn_apply(
    const float* __restrict__ x, const float* __restrict__ gamma,
    const float* __restrict__ beta, const float* __restrict__ part,
    unsigned short* __restrict__ h)
{
    const int q = blockIdx.x, bg = blockIdx.y;
    const int b = bg >> 5, g = bg & 31;
    float s = 0.f, sq = 0.f;
    #pragma unroll
    for (int j = 0; j < 4; ++j) {
        s  += part[(bg * 4 + j) * 2];
        sq += part[(bg * 4 + j) * 2 + 1];
    }
    const float mean = s * (1.f / 65536.f);
    const float rstd = rsqrtf(sq * (1.f / 65536.f) - mean * mean + 1e-5f);

    float gm[16], bt[16];
    #pragma unroll
    for (int c = 0; c < 16; ++c) {
        gm[c] = gamma[g * 16 + c] * rstd;
        bt[c] = beta[g * 16 + c];
    }
    const float* xg = x + (size_t)bg * 65536;
    const int n0 = q * 1024 + threadIdx.x * 4;
    float val[16][4];
    #pragma unroll
    for (int c = 0; c < 16; ++c) {
        f4 v = *(const f4*)&xg[(size_t)c * 4096 + n0];
        val[c][0] = (v.x - mean) * gm[c] + bt[c];
        val[c][1] = (v.y - mean) * gm[c] + bt[c];
        val[c][2] = (v.z - mean) * gm[c] + bt[c];
        val[c][3] = (v.w - mean) * gm[c] + bt[c];
    }
    #pragma unroll
    for (int nn = 0; nn < 4; ++nn) {
        ushort8 v0, v1;
        #pragma unroll
        for (int c = 0; c < 8; ++c)  v0[c]     = f2bf(val[c][nn]);
        #pragma unroll
        for (int c = 8; c < 16; ++c) v1[c - 8] = f2bf(val[c][nn]);
        unsigned short* dst = h + ((size_t)(b * 4096 + n0 + nn)) * 512 + g * 16;
        *(ushort8*)dst = v0;
        *(ushort8*)(dst + 8) = v1;
    }
}

// ---------------------------------------------------------------------------
// 3. bf16 GEMM  C[i,j] = sum_k A[i,k]*Bt[j,k] (+bias, +epilogue)
//    MODE 0 (BM=128): fused QKV. Q cols -> qout (pre-scaled CS), K -> kout,
//                     V -> vt[bh][d][n] (fused transpose).
//    MODE 1 (BM=64):  out fp32 transposed to [B,C,H,W] + residual, bias by i.
// ---------------------------------------------------------------------------
template <int MODE, int BM>
__global__ __launch_bounds__(256, 2) void gemm_bt(
    const unsigned short* __restrict__ A,   // [M,K] bf16
    const unsigned short* __restrict__ Bt,  // [N,K] bf16
    const float* __restrict__ bias0,
    const float* __restrict__ bias1,
    const float* __restrict__ bias2,
    const float* __restrict__ resid,
    void* __restrict__ outp,                // MODE0: qout / MODE1: fp32 out
    unsigned short* __restrict__ kout,
    unsigned short* __restrict__ vtout,
    int M, int N, int K)
{
    constexpr int MT = BM / 32;             // m-frags per wave
    __shared__ __attribute__((aligned(16))) unsigned short As[BM * 32];
    __shared__ __attribute__((aligned(16))) unsigned short Bs[128 * 32];
    const int t = threadIdx.x;
    const int w = t >> 6, lane = t & 63;
    const int l15 = lane & 15, l4 = lane >> 4;
    const int bm = blockIdx.y, bn = blockIdx.x;
    const int wm = (w >> 1) * (BM / 2), wn = (w & 1) * 64;

    f32x4 acc[MT][4] = {};

    const int srow = t >> 2;
    const int sc8  = (t & 3) * 8;

    const unsigned short* gA0 = A  + (size_t)(bm * BM + srow) * K + sc8;
    const unsigned short* gB0 = Bt + (size_t)(bn * 128 + srow) * K + sc8;
    const unsigned short* gB1 = gB0 + (size_t)64 * K;
    unsigned short* lA0 = &As[w * 512];
    unsigned short* lB0 = &Bs[w * 512];
    unsigned short* lB1 = &Bs[2048 + w * 512];

    for (int k0 = 0; k0 < K; k0 += 32) {
        __syncthreads();
        GLL(gA0 + k0, lA0);
        if (BM == 128) GLL(gA0 + (size_t)64 * K + k0, &As[2048 + w * 512]);
        GLL(gB0 + k0, lB0);
        GLL(gB1 + k0, lB1);
        __syncthreads();

        bf16x8 af[MT], bfr[4];
        #pragma unroll
        for (int mt = 0; mt < MT; ++mt)
            af[mt] = *(const bf16x8*)&As[(wm + mt * 16 + l15) * 32 + l4 * 8];
        #pragma unroll
        for (int nt = 0; nt < 4; ++nt)
            bfr[nt] = *(const bf16x8*)&Bs[(wn + nt * 16 + l15) * 32 + l4 * 8];
        #pragma unroll
        for (int mt = 0; mt < MT; ++mt)
            #pragma unroll
            for (int nt = 0; nt < 4; ++nt)
                acc[mt][nt] = __builtin_amdgcn_mfma_f32_16x16x32_bf16(
                    af[mt], bfr[nt], acc[mt][nt], 0, 0, 0);
    }

    if (MODE == 0) {
        unsigned short* qout = (unsigned short*)outp;
        #pragma unroll
        for (int nt = 0; nt < 4; ++nt) {
            int col = bn * 128 + wn + nt * 16 + l15;
            const float* bp = (col < 512) ? bias0 : (col < 1024) ? bias1 : bias2;
            float bv = bp[col & 511];
            if (col < 1024) {                   // Q (pre-scaled) / K compact
                unsigned short* dst = (col < 512) ? qout : kout;
                int cc = col & 511;
                float sc = (col < 512) ? CS : 1.0f;
                #pragma unroll
                for (int mt = 0; mt < MT; ++mt)
                    #pragma unroll
                    for (int r = 0; r < 4; ++r) {
                        int row = bm * BM + wm + mt * 16 + l4 * 4 + r;
                        dst[(size_t)row * 512 + cc] = f2bf((acc[mt][nt][r] + bv) * sc);
                    }
            } else {                            // V -> vt[bh][d][n] directly
                int hd = col - 1024;            // h*64 + d
                #pragma unroll
                for (int mt = 0; mt < MT; ++mt) {
                    int m = bm * BM + wm + mt * 16 + l4 * 4;   // n base (r=0)
                    int bb = m >> 12, n = m & 4095;
                    unsigned u0 = pk2bf(acc[mt][nt][0] + bv, acc[mt][nt][1] + bv);
                    unsigned u1 = pk2bf(acc[mt][nt][2] + bv, acc[mt][nt][3] + bv);
                    unsigned short* dst = vtout +
                        ((size_t)(bb * 8 + (hd >> 6)) * 64 + (hd & 63)) * 4096 + n;
                    *(u32x2*)dst = (u32x2){u0, u1};
                }
            }
        }
    } else {
        float* outF = (float*)outp;
        #pragma unroll
        for (int mt = 0; mt < MT; ++mt)
            #pragma unroll
            for (int nt = 0; nt < 4; ++nt)
                #pragma unroll
                for (int r = 0; r < 4; ++r) {
                    int c = bm * BM + wm + mt * 16 + l4 * 4 + r;
                    int m = bn * 128 + wn + nt * 16 + l15;
                    int b = m >> 12, n = m & 4095;
                    size_t idx = ((size_t)(b * 512 + c)) * 4096 + n;
                    outF[idx] = acc[mt][nt][r] + bias0[c] + resid[idx];
                }
    }
}

// ---------------------------------------------------------------------------
// 4. Flash attention, 32x32x16 MFMA, 64 q/wave, fixed-shift softmax,
//    4-way key split. Block = 4 waves x 64 q = 256 q of one (b,h), 1024 keys.
//    Emits UNNORMALIZED bf16 O-partials (direct dword stores from C-layout,
//    no LDS epilogue) + fp32 l-partials; combine_o merges the 4 splits.
// ---------------------------------------------------------------------------
__global__ __launch_bounds__(256, 4) void attn_kernel(
    const unsigned short* __restrict__ qb, const unsigned short* __restrict__ kb,
    const unsigned short* __restrict__ vt,
    unsigned short* __restrict__ opart, float* __restrict__ lbuf)
{
    __shared__ __attribute__((aligned(16))) unsigned short Ks[64][72];
    __shared__ __attribute__((aligned(16))) unsigned short Vts[64][72];

    const int bh = blockIdx.y, b = bh >> 3, h = bh & 7;
    const int qbase = blockIdx.x * 256;
    const int s = blockIdx.z, ks0 = s * 1024;
    const int t = threadIdx.x, w = t >> 6, lane = t & 63;
    const int l31 = lane & 31, h5 = lane >> 5;

    const unsigned short* Qg = qb + ((size_t)(b * 4096 + qbase + w * 64)) * 512 + h * 64;
    const unsigned short* Kg = kb + ((size_t)(b * 4096 + ks0)) * 512 + h * 64;
    const unsigned short* Vg = vt + ((size_t)bh) * 64 * 4096 + ks0;

    // Q fragments (B-operand, persistent): q=qt*32+l31, d=kc*16+h5*8+j
    bf16x8 qf[2][4];
    #pragma unroll
    for (int qt = 0; qt < 2; ++qt)
        #pragma unroll
        for (int kc = 0; kc < 4; ++kc)
            qf[qt][kc] = *(const bf16x8*)(Qg + (size_t)(qt * 32 + l31) * 512 + kc * 16 + h5 * 8);

    f32x16 Oacc[2][2] = {};      // [dt][qt], C-layout: col=q, row=d
    float li[2] = {0.f, 0.f};

    // staging: 256 threads x 32 B for each of K (8 KB) and V^T (8 KB)
    const int sr = t >> 2, sc = (t & 3) * 16;
    const unsigned short* gK = Kg + (size_t)sr * 512 + sc;
    const unsigned short* gV = Vg + (size_t)sr * 4096 + sc;
    unsigned short* lK = &Ks[sr][sc];
    unsigned short* lV = &Vts[sr][sc];

    ushort8 kr[2], vr[2];
    kr[0] = *(const ushort8*)(gK);
    kr[1] = *(const ushort8*)(gK + 8);
    vr[0] = *(const ushort8*)(gV);
    vr[1] = *(const ushort8*)(gV + 8);

    for (int kt = 0; kt < 16; ++kt) {
        __syncthreads();
        *(ushort8*)(lK)     = kr[0];
        *(ushort8*)(lK + 8) = kr[1];
        *(ushort8*)(lV)     = vr[0];
        *(ushort8*)(lV + 8) = vr[1];
        __syncthreads();
        if (kt < 15) {   // prefetch next tile into registers
            const unsigned short* nk = gK + (size_t)(kt + 1) * 64 * 512;
            const unsigned short* nv = gV + (kt + 1) * 64;
            kr[0] = *(const ushort8*)(nk);
            kr[1] = *(const ushort8*)(nk + 8);
            vr[0] = *(const ushort8*)(nv);
            vr[1] = *(const ushort8*)(nv + 8);
        }

        // ---- S^T tiles: St[qt][ct] = K(ct) @ Q(qt)^T (scale pre-folded) ----
        f32x16 St[2][2] = {};
        #pragma unroll
        for (int ct = 0; ct < 2; ++ct)
            #pragma unroll
            for (int kc = 0; kc < 4; ++kc) {
                bf16x8 kf = *(const bf16x8*)&Ks[ct * 32 + l31][kc * 16 + h5 * 8];
                St[0][ct] = __builtin_amdgcn_mfma_f32_32x32x16_bf16(kf, qf[0][kc], St[0][ct], 0, 0, 0);
                St[1][ct] = __builtin_amdgcn_mfma_f32_32x32x16_bf16(kf, qf[1][kc], St[1][ct], 0, 0, 0);
            }

        // ---- p = exp2(S'); per-lane row sums; pack to PV B-operand ----
        union PU { unsigned u[4]; bf16x8 v; };
        PU pf[2][4];
        #pragma unroll
        for (int qt = 0; qt < 2; ++qt) {
            #pragma unroll
            for (int ct = 0; ct < 2; ++ct)
                #pragma unroll
                for (int r = 0; r < 16; ++r)
                    St[qt][ct][r] = EXP2(St[qt][ct][r]);
            float s0 = 0.f, s1 = 0.f;
            #pragma unroll
            for (int ct = 0; ct < 2; ++ct) {
                s0 += ((St[qt][ct][0] + St[qt][ct][1]) + (St[qt][ct][2] + St[qt][ct][3]))
                    + ((St[qt][ct][4] + St[qt][ct][5]) + (St[qt][ct][6] + St[qt][ct][7]));
                s1 += ((St[qt][ct][8] + St[qt][ct][9]) + (St[qt][ct][10] + St[qt][ct][11]))
                    + ((St[qt][ct][12] + St[qt][ct][13]) + (St[qt][ct][14] + St[qt][ct][15]));
            }
            li[qt] += s0 + s1;

            #pragma unroll
            for (int ct = 0; ct < 2; ++ct) {
                unsigned pk0 = pk2bf(St[qt][ct][0],  St[qt][ct][1]);
                unsigned pk1 = pk2bf(St[qt][ct][2],  St[qt][ct][3]);
                unsigned pk2 = pk2bf(St[qt][ct][4],  St[qt][ct][5]);
                unsigned pk3 = pk2bf(St[qt][ct][6],  St[qt][ct][7]);
                unsigned pk4 = pk2bf(St[qt][ct][8],  St[qt][ct][9]);
                unsigned pk5 = pk2bf(St[qt][ct][10], St[qt][ct][11]);
                unsigned pk6 = pk2bf(St[qt][ct][12], St[qt][ct][13]);
                unsigned pk7 = pk2bf(St[qt][ct][14], St[qt][ct][15]);
                pl32swap(pk0, pk2); pl32swap(pk1, pk3);
                pl32swap(pk4, pk6); pl32swap(pk5, pk7);
                pf[qt][ct * 2].u[0] = pk0; pf[qt][ct * 2].u[1] = pk1;
                pf[qt][ct * 2].u[2] = pk2; pf[qt][ct * 2].u[3] = pk3;
                pf[qt][ct * 2 + 1].u[0] = pk4; pf[qt][ct * 2 + 1].u[1] = pk5;
                pf[qt][ct * 2 + 1].u[2] = pk6; pf[qt][ct * 2 + 1].u[3] = pk7;
            }
        }

        // ---- O^T += V^T(dt) @ P^T(kk) ----
        #pragma unroll
        for (int kk = 0; kk < 4; ++kk)
            #pragma unroll
            for (int dt = 0; dt < 2; ++dt) {
                bf16x8 vf = *(const bf16x8*)&Vts[dt * 32 + l31][kk * 16 + h5 * 8];
                Oacc[dt][0] = __builtin_amdgcn_mfma_f32_32x32x16_bf16(vf, pf[0][kk].v, Oacc[dt][0], 0, 0, 0);
                Oacc[dt][1] = __builtin_amdgcn_mfma_f32_32x32x16_bf16(vf, pf[1][kk].v, Oacc[dt][1], 0, 0, 0);
            }
    }

    // ---- epilogue: UNNORMALIZED partials, direct dword stores (no LDS) ----
    #pragma unroll
    for (int qt = 0; qt < 2; ++qt) {
        float lf = li[qt] + __shfl_xor(li[qt], 32, 64);
        size_t qrow = ((size_t)s * 16 + bh) * 4096 + qbase + w * 64 + qt * 32 + l31;
        if (h5 == 0) lbuf[qrow] = lf;
        unsigned short* orow = opart + qrow * 64;
        #pragma unroll
        for (int dt = 0; dt < 2; ++dt)
            #pragma unroll
            for (int p = 0; p < 8; ++p) {
                int d = dt * 32 + 2 * (p & 1) + 8 * (p >> 1) + 4 * h5;
                unsigned u = pk2bf(Oacc[dt][qt][2 * p], Oacc[dt][qt][2 * p + 1]);
                *(unsigned*)(orow + d) = u;
            }
    }
}

// ---------------------------------------------------------------------------
// 5. Combine 4 key-split partials: O = sum(Os)/sum(ls) -> [B*N, C] bf16
// ---------------------------------------------------------------------------
__global__ __launch_bounds__(256) void combine_o(
    const unsigned short* __restrict__ opart, const float* __restrict__ lbuf,
    unsigned short* __restrict__ o)
{
    int gid = blockIdx.x * 256 + threadIdx.x;   // 524288 = 65536 rows x 8 chunks
    int row = gid >> 3, c8 = gid & 7;           // row = bh*4096 + q
    int bh = row >> 12, q = row & 4095;
    int b = bh >> 3, h = bh & 7;
    float lsum = lbuf[row] + lbuf[65536 + row] + lbuf[131072 + row] + lbuf[196608 + row];
    float inv = 1.f / lsum;
    float acc[8] = {};
    #pragma unroll
    for (int sp = 0; sp < 4; ++sp) {
        ushort8 ov = *(const ushort8*)(opart + ((size_t)sp * 65536 + row) * 64 + c8 * 8);
        #pragma unroll
        for (int i = 0; i < 8; ++i) acc[i] += bf2f(ov[i]);
    }
    ushort8 r;
    #pragma unroll
    for (int i = 0; i < 8; ++i) r[i] = f2bf(acc[i] * inv);
    *(ushort8*)(o + ((size_t)(b * 4096 + q)) * 512 + h * 64 + c8 * 8) = r;
}

// ---------------------------------------------------------------------------
// launch
// ---------------------------------------------------------------------------
extern "C" void kernel_launch(void* const* d_in, const int* in_sizes, int n_in,
                              void* d_out, int out_size, void* d_ws, size_t ws_size,
                              hipStream_t stream) {
    const float* x     = (const float*)d_in[0];
    const float* gamma = (const float*)d_in[1];
    const float* beta  = (const float*)d_in[2];
    const float* Wq    = (const float*)d_in[3];
    const float* bq    = (const float*)d_in[4];
    const float* Wk    = (const float*)d_in[5];
    const float* bk    = (const float*)d_in[6];
    const float* Wv    = (const float*)d_in[7];
    const float* bv    = (const float*)d_in[8];
    const float* Wo    = (const float*)d_in[9];
    const float* bo    = (const float*)d_in[10];
    float* out = (float*)d_out;

    char* ws = (char*)d_ws;
    const size_t MB = 1024 * 1024;
    // Overlay layout (≈59.2 MB):
    //   @0  qbuf 8MB
    //   @8  kbuf 8MB   -> reused as Obuf by combine_o (kbuf dead post-attn)
    //   @16 vtb  8MB
    //   @24 h    8MB (GN out, dead after QKV GEMM) -> opart[0] overlays it
    //   @24 opart 32MB ([24,56))
    //   @56 wb   2MB
    //   @58 gnpart 4KB
    //   @58.25 lbuf 1MB
    unsigned short* qbuf   = (unsigned short*)(ws);
    unsigned short* kbuf   = (unsigned short*)(ws + 8 * MB);
    unsigned short* obuf   = kbuf;
    unsigned short* vtb    = (unsigned short*)(ws + 16 * MB);
    unsigned short* h      = (unsigned short*)(ws + 24 * MB);
    unsigned short* opart  = (unsigned short*)(ws + 24 * MB);
    unsigned short* wb     = (unsigned short*)(ws + 56 * MB);
    float*          gnpart = (float*)(ws + 58 * MB);
    float*          lbuf   = (float*)(ws + 58 * MB + 256 * 1024);

    convert_w<<<dim3(4096), dim3(256), 0, stream>>>(Wq, Wk, Wv, Wo, wb);
    gn_stats<<<dim3(4, 64), dim3(256), 0, stream>>>(x, gnpart);
    gn_apply<<<dim3(4, 64), dim3(256), 0, stream>>>(x, gamma, beta, gnpart, h);

    // fused qkv: Q->qbuf (CS-scaled), K->kbuf, V->vtb (transposed)
    gemm_bt<0, 128><<<dim3(12, 64), dim3(256), 0, stream>>>(
        h, wb, bq, bk, bv, nullptr, qbuf, kbuf, vtb, 8192, 1536, 512);

    attn_kernel<<<dim3(16, 16, 4), dim3(256), 0, stream>>>(qbuf, kbuf, vtb, opart, lbuf);
    combine_o<<<dim3(2048), dim3(256), 0, stream>>>(opart, lbuf, obuf);

    // out[b,c,n] = x + (O @ Wo^T + bo)^T : C[c, m] with A=Wo, Bt=O, BM=64
    gemm_bt<1, 64><<<dim3(64, 8), dim3(256), 0, stream>>>(
        wb + 786432, obuf, bo, nullptr, nullptr, x, out, nullptr, nullptr, 512, 8192, 512);
}

// Round 7
// 280.127 us; speedup vs baseline: 2.3863x; 2.3863x over previous
//
#include <hip/hip_runtime.h>
#include <cstdint>
#include <cstddef>

typedef __bf16 bf16x8 __attribute__((ext_vector_type(8)));
typedef float f32x4 __attribute__((ext_vector_type(4)));
typedef float f32x16 __attribute__((ext_vector_type(16)));
typedef unsigned short ushort8 __attribute__((ext_vector_type(8)));
typedef unsigned u32x2 __attribute__((ext_vector_type(2)));
typedef float f4 __attribute__((ext_vector_type(4)));

__device__ __forceinline__ unsigned short f2bf(float f) {
    __bf16 b = (__bf16)f;
    return *(unsigned short*)&b;
}
__device__ __forceinline__ unsigned pk2bf(float a, float b) {
    __bf16 x = (__bf16)a, y = (__bf16)b;
    unsigned short ux = *(unsigned short*)&x, uy = *(unsigned short*)&y;
    return (unsigned)ux | ((unsigned)uy << 16);
}
__device__ __forceinline__ float bf2f(unsigned short u) {
    union { unsigned u; float f; } v; v.u = ((unsigned)u) << 16; return v.f;
}

#if __has_builtin(__builtin_amdgcn_exp2f)
#define EXP2(x) __builtin_amdgcn_exp2f(x)
#else
#define EXP2(x) exp2f(x)
#endif

// exchange high 32 lanes of x with low 32 lanes of y (v_permlane32_swap_b32)
__device__ __forceinline__ void pl32swap(unsigned& x, unsigned& y) {
#if __has_builtin(__builtin_amdgcn_permlane32_swap)
    auto r = __builtin_amdgcn_permlane32_swap(x, y, false, false);
    x = r[0]; y = r[1];
#else
    unsigned xs = (unsigned)__shfl_xor((int)x, 32, 64);
    unsigned ys = (unsigned)__shfl_xor((int)y, 32, 64);
    bool lo = ((threadIdx.x & 63) < 32);
    unsigned nx = lo ? x : ys;
    unsigned ny = lo ? xs : y;
    x = nx; y = ny;
#endif
}

#define GLL(g, l) __builtin_amdgcn_global_load_lds( \
    (__attribute__((address_space(1))) void*)(g), \
    (__attribute__((address_space(3))) void*)(l), 16, 0, 0)

#define CS 0.18033688011112042f   /* 0.125 * log2(e) */

// ---------------------------------------------------------------------------
// 1. Convert the four 512x512 fp32 weight matrices to bf16 (concatenated).
// ---------------------------------------------------------------------------
__global__ __launch_bounds__(256) void convert_w(
    const float* __restrict__ wq, const float* __restrict__ wk,
    const float* __restrict__ wv, const float* __restrict__ wo,
    unsigned short* __restrict__ out)
{
    int i = blockIdx.x * 256 + threadIdx.x;
    const float* src = (i < 262144) ? wq : (i < 524288) ? wk : (i < 786432) ? wv : wo;
    out[i] = f2bf(src[i & 262143]);
}

// ---------------------------------------------------------------------------
// 2a. GroupNorm stats: grid (4 quarters, 64 b*g); partials -> part[(bg*4+q)*2]
// ---------------------------------------------------------------------------
__global__ __launch_bounds__(256) void gn_stats(
    const float* __restrict__ x, float* __restrict__ part)
{
    const int q = blockIdx.x, bg = blockIdx.y;
    const f4* xv = (const f4*)(x + (size_t)bg * 65536 + q * 16384);
    float s = 0.f, sq = 0.f;
    for (int i = threadIdx.x; i < 4096; i += 256) {
        f4 v = xv[i];
        s  += v.x + v.y + v.z + v.w;
        sq += v.x * v.x + v.y * v.y + v.z * v.z + v.w * v.w;
    }
    #pragma unroll
    for (int off = 32; off > 0; off >>= 1) {
        s  += __shfl_xor(s, off, 64);
        sq += __shfl_xor(sq, off, 64);
    }
    __shared__ float red[8];
    const int w = threadIdx.x >> 6, lane = threadIdx.x & 63;
    if (lane == 0) { red[w] = s; red[4 + w] = sq; }
    __syncthreads();
    if (threadIdx.x == 0) {
        part[(bg * 4 + q) * 2]     = red[0] + red[1] + red[2] + red[3];
        part[(bg * 4 + q) * 2 + 1] = red[4] + red[5] + red[6] + red[7];
    }
}

// ---------------------------------------------------------------------------
// 2b. GroupNorm apply -> h bf16 in [B*N, C] layout.
// ---------------------------------------------------------------------------
__global__ __launch_bounds__(256) void gn_apply(
    const float* __restrict__ x, const float* __restrict__ gamma,
    const float* __restrict__ beta, const float* __restrict__ part,
    unsigned short* __restrict__ h)
{
    const int q = blockIdx.x, bg = blockIdx.y;
    const int b = bg >> 5, g = bg & 31;
    float s = 0.f, sq = 0.f;
    #pragma unroll
    for (int j = 0; j < 4; ++j) {
        s  += part[(bg * 4 + j) * 2];
        sq += part[(bg * 4 + j) * 2 + 1];
    }
    const float mean = s * (1.f / 65536.f);
    const float rstd = rsqrtf(sq * (1.f / 65536.f) - mean * mean + 1e-5f);

    float gm[16], bt[16];
    #pragma unroll
    for (int c = 0; c < 16; ++c) {
        gm[c] = gamma[g * 16 + c] * rstd;
        bt[c] = beta[g * 16 + c];
    }
    const float* xg = x + (size_t)bg * 65536;
    const int n0 = q * 1024 + threadIdx.x * 4;
    float val[16][4];
    #pragma unroll
    for (int c = 0; c < 16; ++c) {
        f4 v = *(const f4*)&xg[(size_t)c * 4096 + n0];
        val[c][0] = (v.x - mean) * gm[c] + bt[c];
        val[c][1] = (v.y - mean) * gm[c] + bt[c];
        val[c][2] = (v.z - mean) * gm[c] + bt[c];
        val[c][3] = (v.w - mean) * gm[c] + bt[c];
    }
    #pragma unroll
    for (int nn = 0; nn < 4; ++nn) {
        ushort8 v0, v1;
        #pragma unroll
        for (int c = 0; c < 8; ++c)  v0[c]     = f2bf(val[c][nn]);
        #pragma unroll
        for (int c = 8; c < 16; ++c) v1[c - 8] = f2bf(val[c][nn]);
        unsigned short* dst = h + ((size_t)(b * 4096 + n0 + nn)) * 512 + g * 16;
        *(ushort8*)dst = v0;
        *(ushort8*)(dst + 8) = v1;
    }
}

// ---------------------------------------------------------------------------
// 3. bf16 GEMM  C[i,j] = sum_k A[i,k]*Bt[j,k] (+bias, +epilogue)
//    MODE 0 (BM=128): fused QKV. Q cols -> qout (pre-scaled CS), K -> kout,
//                     V -> vt[bh][d][n] (fused transpose).
//    MODE 1 (BM=64):  out fp32 transposed to [B,C,H,W] + residual, bias by i.
// ---------------------------------------------------------------------------
template <int MODE, int BM>
__global__ __launch_bounds__(256, 2) void gemm_bt(
    const unsigned short* __restrict__ A,   // [M,K] bf16
    const unsigned short* __restrict__ Bt,  // [N,K] bf16
    const float* __restrict__ bias0,
    const float* __restrict__ bias1,
    const float* __restrict__ bias2,
    const float* __restrict__ resid,
    void* __restrict__ outp,                // MODE0: qout / MODE1: fp32 out
    unsigned short* __restrict__ kout,
    unsigned short* __restrict__ vtout,
    int M, int N, int K)
{
    constexpr int MT = BM / 32;             // m-frags per wave
    __shared__ __attribute__((aligned(16))) unsigned short As[BM * 32];
    __shared__ __attribute__((aligned(16))) unsigned short Bs[128 * 32];
    const int t = threadIdx.x;
    const int w = t >> 6, lane = t & 63;
    const int l15 = lane & 15, l4 = lane >> 4;
    const int bm = blockIdx.y, bn = blockIdx.x;
    const int wm = (w >> 1) * (BM / 2), wn = (w & 1) * 64;

    f32x4 acc[MT][4] = {};

    const int srow = t >> 2;
    const int sc8  = (t & 3) * 8;

    const unsigned short* gA0 = A  + (size_t)(bm * BM + srow) * K + sc8;
    const unsigned short* gB0 = Bt + (size_t)(bn * 128 + srow) * K + sc8;
    const unsigned short* gB1 = gB0 + (size_t)64 * K;
    unsigned short* lA0 = &As[w * 512];
    unsigned short* lB0 = &Bs[w * 512];
    unsigned short* lB1 = &Bs[2048 + w * 512];

    for (int k0 = 0; k0 < K; k0 += 32) {
        __syncthreads();
        GLL(gA0 + k0, lA0);
        if (BM == 128) GLL(gA0 + (size_t)64 * K + k0, &As[2048 + w * 512]);
        GLL(gB0 + k0, lB0);
        GLL(gB1 + k0, lB1);
        __syncthreads();

        bf16x8 af[MT], bfr[4];
        #pragma unroll
        for (int mt = 0; mt < MT; ++mt)
            af[mt] = *(const bf16x8*)&As[(wm + mt * 16 + l15) * 32 + l4 * 8];
        #pragma unroll
        for (int nt = 0; nt < 4; ++nt)
            bfr[nt] = *(const bf16x8*)&Bs[(wn + nt * 16 + l15) * 32 + l4 * 8];
        #pragma unroll
        for (int mt = 0; mt < MT; ++mt)
            #pragma unroll
            for (int nt = 0; nt < 4; ++nt)
                acc[mt][nt] = __builtin_amdgcn_mfma_f32_16x16x32_bf16(
                    af[mt], bfr[nt], acc[mt][nt], 0, 0, 0);
    }

    if (MODE == 0) {
        unsigned short* qout = (unsigned short*)outp;
        #pragma unroll
        for (int nt = 0; nt < 4; ++nt) {
            int col = bn * 128 + wn + nt * 16 + l15;
            const float* bp = (col < 512) ? bias0 : (col < 1024) ? bias1 : bias2;
            float bv = bp[col & 511];
            if (col < 1024) {                   // Q (pre-scaled) / K compact
                unsigned short* dst = (col < 512) ? qout : kout;
                int cc = col & 511;
                float sc = (col < 512) ? CS : 1.0f;
                #pragma unroll
                for (int mt = 0; mt < MT; ++mt)
                    #pragma unroll
                    for (int r = 0; r < 4; ++r) {
                        int row = bm * BM + wm + mt * 16 + l4 * 4 + r;
                        dst[(size_t)row * 512 + cc] = f2bf((acc[mt][nt][r] + bv) * sc);
                    }
            } else {                            // V -> vt[bh][d][n] directly
                int hd = col - 1024;            // h*64 + d
                #pragma unroll
                for (int mt = 0; mt < MT; ++mt) {
                    int m = bm * BM + wm + mt * 16 + l4 * 4;   // n base (r=0)
                    int bb = m >> 12, n = m & 4095;
                    unsigned u0 = pk2bf(acc[mt][nt][0] + bv, acc[mt][nt][1] + bv);
                    unsigned u1 = pk2bf(acc[mt][nt][2] + bv, acc[mt][nt][3] + bv);
                    unsigned short* dst = vtout +
                        ((size_t)(bb * 8 + (hd >> 6)) * 64 + (hd & 63)) * 4096 + n;
                    *(u32x2*)dst = (u32x2){u0, u1};
                }
            }
        }
    } else {
        float* outF = (float*)outp;
        #pragma unroll
        for (int mt = 0; mt < MT; ++mt)
            #pragma unroll
            for (int nt = 0; nt < 4; ++nt)
                #pragma unroll
                for (int r = 0; r < 4; ++r) {
                    int c = bm * BM + wm + mt * 16 + l4 * 4 + r;
                    int m = bn * 128 + wn + nt * 16 + l15;
                    int b = m >> 12, n = m & 4095;
                    size_t idx = ((size_t)(b * 512 + c)) * 4096 + n;
                    outF[idx] = acc[mt][nt][r] + bias0[c] + resid[idx];
                }
    }
}

// ---------------------------------------------------------------------------
// 4. Flash attention, 32x32x16 MFMA, 64 q/wave, fixed-shift softmax,
//    4-way key split. Block = 4 waves x 64 q = 256 q of one (b,h), 1024 keys.
//    ct-SEQUENTIAL inner loop: for each 32-key column tile: S-MFMA -> softmax
//    -> PV. Only one St pair (32 regs) live at a time -> fits 3 waves/SIMD
//    without spill (R6's launch_bounds(256,4) forced a 2.4 GB scratch spill).
//    Emits UNNORMALIZED bf16 O-partials + fp32 l-partials; combine_o merges.
// ---------------------------------------------------------------------------
__global__ __launch_bounds__(256, 3) void attn_kernel(
    const unsigned short* __restrict__ qb, const unsigned short* __restrict__ kb,
    const unsigned short* __restrict__ vt,
    unsigned short* __restrict__ opart, float* __restrict__ lbuf)
{
    __shared__ __attribute__((aligned(16))) unsigned short Ks[64][72];
    __shared__ __attribute__((aligned(16))) unsigned short Vts[64][72];

    const int bh = blockIdx.y, b = bh >> 3, h = bh & 7;
    const int qbase = blockIdx.x * 256;
    const int s = blockIdx.z, ks0 = s * 1024;
    const int t = threadIdx.x, w = t >> 6, lane = t & 63;
    const int l31 = lane & 31, h5 = lane >> 5;

    const unsigned short* Qg = qb + ((size_t)(b * 4096 + qbase + w * 64)) * 512 + h * 64;
    const unsigned short* Kg = kb + ((size_t)(b * 4096 + ks0)) * 512 + h * 64;
    const unsigned short* Vg = vt + ((size_t)bh) * 64 * 4096 + ks0;

    // Q fragments (B-operand, persistent): q=qt*32+l31, d=kc*16+h5*8+j
    bf16x8 qf[2][4];
    #pragma unroll
    for (int qt = 0; qt < 2; ++qt)
        #pragma unroll
        for (int kc = 0; kc < 4; ++kc)
            qf[qt][kc] = *(const bf16x8*)(Qg + (size_t)(qt * 32 + l31) * 512 + kc * 16 + h5 * 8);

    f32x16 Oacc[2][2] = {};      // [dt][qt], C-layout: col=q, row=d
    float li[2] = {0.f, 0.f};

    // staging: 256 threads x 32 B for each of K (8 KB) and V^T (8 KB)
    const int sr = t >> 2, sc = (t & 3) * 16;
    const unsigned short* gK = Kg + (size_t)sr * 512 + sc;
    const unsigned short* gV = Vg + (size_t)sr * 4096 + sc;
    unsigned short* lK = &Ks[sr][sc];
    unsigned short* lV = &Vts[sr][sc];

    ushort8 kr[2], vr[2];
    kr[0] = *(const ushort8*)(gK);
    kr[1] = *(const ushort8*)(gK + 8);
    vr[0] = *(const ushort8*)(gV);
    vr[1] = *(const ushort8*)(gV + 8);

    for (int kt = 0; kt < 16; ++kt) {
        __syncthreads();
        *(ushort8*)(lK)     = kr[0];
        *(ushort8*)(lK + 8) = kr[1];
        *(ushort8*)(lV)     = vr[0];
        *(ushort8*)(lV + 8) = vr[1];
        __syncthreads();
        if (kt < 15) {   // prefetch next tile into registers
            const unsigned short* nk = gK + (size_t)(kt + 1) * 64 * 512;
            const unsigned short* nv = gV + (kt + 1) * 64;
            kr[0] = *(const ushort8*)(nk);
            kr[1] = *(const ushort8*)(nk + 8);
            vr[0] = *(const ushort8*)(nv);
            vr[1] = *(const ushort8*)(nv + 8);
        }

        // ---- per 32-key column tile: S -> softmax -> PV (St short-lived) ----
        #pragma unroll
        for (int ct = 0; ct < 2; ++ct) {
            f32x16 St0 = {}, St1 = {};
            #pragma unroll
            for (int kc = 0; kc < 4; ++kc) {
                bf16x8 kf = *(const bf16x8*)&Ks[ct * 32 + l31][kc * 16 + h5 * 8];
                St0 = __builtin_amdgcn_mfma_f32_32x32x16_bf16(kf, qf[0][kc], St0, 0, 0, 0);
                St1 = __builtin_amdgcn_mfma_f32_32x32x16_bf16(kf, qf[1][kc], St1, 0, 0, 0);
            }

            #pragma unroll
            for (int r = 0; r < 16; ++r) St0[r] = EXP2(St0[r]);
            #pragma unroll
            for (int r = 0; r < 16; ++r) St1[r] = EXP2(St1[r]);

            float a0 = 0.f, a1 = 0.f;
            #pragma unroll
            for (int r = 0; r < 16; ++r) { a0 += St0[r]; a1 += St1[r]; }
            li[0] += a0; li[1] += a1;

            union PU { unsigned u[4]; bf16x8 v; };
            PU pf0[2], pf1[2];
            {
                unsigned p0 = pk2bf(St0[0],  St0[1]),  p1 = pk2bf(St0[2],  St0[3]);
                unsigned p2 = pk2bf(St0[4],  St0[5]),  p3 = pk2bf(St0[6],  St0[7]);
                unsigned p4 = pk2bf(St0[8],  St0[9]),  p5 = pk2bf(St0[10], St0[11]);
                unsigned p6 = pk2bf(St0[12], St0[13]), p7 = pk2bf(St0[14], St0[15]);
                pl32swap(p0, p2); pl32swap(p1, p3);
                pl32swap(p4, p6); pl32swap(p5, p7);
                pf0[0].u[0] = p0; pf0[0].u[1] = p1; pf0[0].u[2] = p2; pf0[0].u[3] = p3;
                pf0[1].u[0] = p4; pf0[1].u[1] = p5; pf0[1].u[2] = p6; pf0[1].u[3] = p7;
            }
            {
                unsigned p0 = pk2bf(St1[0],  St1[1]),  p1 = pk2bf(St1[2],  St1[3]);
                unsigned p2 = pk2bf(St1[4],  St1[5]),  p3 = pk2bf(St1[6],  St1[7]);
                unsigned p4 = pk2bf(St1[8],  St1[9]),  p5 = pk2bf(St1[10], St1[11]);
                unsigned p6 = pk2bf(St1[12], St1[13]), p7 = pk2bf(St1[14], St1[15]);
                pl32swap(p0, p2); pl32swap(p1, p3);
                pl32swap(p4, p6); pl32swap(p5, p7);
                pf1[0].u[0] = p0; pf1[0].u[1] = p1; pf1[0].u[2] = p2; pf1[0].u[3] = p3;
                pf1[1].u[0] = p4; pf1[1].u[1] = p5; pf1[1].u[2] = p6; pf1[1].u[3] = p7;
            }

            #pragma unroll
            for (int kkl = 0; kkl < 2; ++kkl)
                #pragma unroll
                for (int dt = 0; dt < 2; ++dt) {
                    bf16x8 vf = *(const bf16x8*)&Vts[dt * 32 + l31][(ct * 2 + kkl) * 16 + h5 * 8];
                    Oacc[dt][0] = __builtin_amdgcn_mfma_f32_32x32x16_bf16(vf, pf0[kkl].v, Oacc[dt][0], 0, 0, 0);
                    Oacc[dt][1] = __builtin_amdgcn_mfma_f32_32x32x16_bf16(vf, pf1[kkl].v, Oacc[dt][1], 0, 0, 0);
                }
        }
    }

    // ---- epilogue: UNNORMALIZED partials, direct dword stores (no LDS) ----
    #pragma unroll
    for (int qt = 0; qt < 2; ++qt) {
        float lf = li[qt] + __shfl_xor(li[qt], 32, 64);
        size_t qrow = ((size_t)s * 16 + bh) * 4096 + qbase + w * 64 + qt * 32 + l31;
        if (h5 == 0) lbuf[qrow] = lf;
        unsigned short* orow = opart + qrow * 64;
        #pragma unroll
        for (int dt = 0; dt < 2; ++dt)
            #pragma unroll
            for (int p = 0; p < 8; ++p) {
                int d = dt * 32 + 2 * (p & 1) + 8 * (p >> 1) + 4 * h5;
                unsigned u = pk2bf(Oacc[dt][qt][2 * p], Oacc[dt][qt][2 * p + 1]);
                *(unsigned*)(orow + d) = u;
            }
    }
}

// ---------------------------------------------------------------------------
// 5. Combine 4 key-split partials: O = sum(Os)/sum(ls) -> [B*N, C] bf16
// ---------------------------------------------------------------------------
__global__ __launch_bounds__(256) void combine_o(
    const unsigned short* __restrict__ opart, const float* __restrict__ lbuf,
    unsigned short* __restrict__ o)
{
    int gid = blockIdx.x * 256 + threadIdx.x;   // 524288 = 65536 rows x 8 chunks
    int row = gid >> 3, c8 = gid & 7;           // row = bh*4096 + q
    int bh = row >> 12, q = row & 4095;
    int b = bh >> 3, h = bh & 7;
    float lsum = lbuf[row] + lbuf[65536 + row] + lbuf[131072 + row] + lbuf[196608 + row];
    float inv = 1.f / lsum;
    float acc[8] = {};
    #pragma unroll
    for (int sp = 0; sp < 4; ++sp) {
        ushort8 ov = *(const ushort8*)(opart + ((size_t)sp * 65536 + row) * 64 + c8 * 8);
        #pragma unroll
        for (int i = 0; i < 8; ++i) acc[i] += bf2f(ov[i]);
    }
    ushort8 r;
    #pragma unroll
    for (int i = 0; i < 8; ++i) r[i] = f2bf(acc[i] * inv);
    *(ushort8*)(o + ((size_t)(b * 4096 + q)) * 512 + h * 64 + c8 * 8) = r;
}

// ---------------------------------------------------------------------------
// launch
// ---------------------------------------------------------------------------
extern "C" void kernel_launch(void* const* d_in, const int* in_sizes, int n_in,
                              void* d_out, int out_size, void* d_ws, size_t ws_size,
                              hipStream_t stream) {
    const float* x     = (const float*)d_in[0];
    const float* gamma = (const float*)d_in[1];
    const float* beta  = (const float*)d_in[2];
    const float* Wq    = (const float*)d_in[3];
    const float* bq    = (const float*)d_in[4];
    const float* Wk    = (const float*)d_in[5];
    const float* bk    = (const float*)d_in[6];
    const float* Wv    = (const float*)d_in[7];
    const float* bv    = (const float*)d_in[8];
    const float* Wo    = (const float*)d_in[9];
    const float* bo    = (const float*)d_in[10];
    float* out = (float*)d_out;

    char* ws = (char*)d_ws;
    const size_t MB = 1024 * 1024;
    // Overlay layout (≈59.2 MB):
    //   @0  qbuf 8MB
    //   @8  kbuf 8MB   -> reused as Obuf by combine_o (kbuf dead post-attn)
    //   @16 vtb  8MB
    //   @24 h    8MB (GN out, dead after QKV GEMM) -> opart[0] overlays it
    //   @24 opart 32MB ([24,56))
    //   @56 wb   2MB
    //   @58 gnpart 4KB
    //   @58.25 lbuf 1MB
    unsigned short* qbuf   = (unsigned short*)(ws);
    unsigned short* kbuf   = (unsigned short*)(ws + 8 * MB);
    unsigned short* obuf   = kbuf;
    unsigned short* vtb    = (unsigned short*)(ws + 16 * MB);
    unsigned short* h      = (unsigned short*)(ws + 24 * MB);
    unsigned short* opart  = (unsigned short*)(ws + 24 * MB);
    unsigned short* wb     = (unsigned short*)(ws + 56 * MB);
    float*          gnpart = (float*)(ws + 58 * MB);
    float*          lbuf   = (float*)(ws + 58 * MB + 256 * 1024);

    convert_w<<<dim3(4096), dim3(256), 0, stream>>>(Wq, Wk, Wv, Wo, wb);
    gn_stats<<<dim3(4, 64), dim3(256), 0, stream>>>(x, gnpart);
    gn_apply<<<dim3(4, 64), dim3(256), 0, stream>>>(x, gamma, beta, gnpart, h);

    // fused qkv: Q->qbuf (CS-scaled), K->kbuf, V->vtb (transposed)
    gemm_bt<0, 128><<<dim3(12, 64), dim3(256), 0, stream>>>(
        h, wb, bq, bk, bv, nullptr, qbuf, kbuf, vtb, 8192, 1536, 512);

    attn_kernel<<<dim3(16, 16, 4), dim3(256), 0, stream>>>(qbuf, kbuf, vtb, opart, lbuf);
    combine_o<<<dim3(2048), dim3(256), 0, stream>>>(opart, lbuf, obuf);

    // out[b,c,n] = x + (O @ Wo^T + bo)^T : C[c, m] with A=Wo, Bt=O, BM=64
    gemm_bt<1, 64><<<dim3(64, 8), dim3(256), 0, stream>>>(
        wb + 786432, obuf, bo, nullptr, nullptr, x, out, nullptr, nullptr, 512, 8192, 512);
}

// Round 8
// 226.566 us; speedup vs baseline: 2.9505x; 1.2364x over previous
//
#include <hip/hip_runtime.h>
#include <cstdint>
#include <cstddef>

typedef __bf16 bf16x8 __attribute__((ext_vector_type(8)));
typedef float f32x4 __attribute__((ext_vector_type(4)));
typedef float f32x16 __attribute__((ext_vector_type(16)));
typedef unsigned short ushort8 __attribute__((ext_vector_type(8)));
typedef unsigned u32x2 __attribute__((ext_vector_type(2)));
typedef float f4 __attribute__((ext_vector_type(4)));

__device__ __forceinline__ unsigned short f2bf(float f) {
    __bf16 b = (__bf16)f;
    return *(unsigned short*)&b;
}
__device__ __forceinline__ unsigned pk2bf(float a, float b) {
    __bf16 x = (__bf16)a, y = (__bf16)b;
    unsigned short ux = *(unsigned short*)&x, uy = *(unsigned short*)&y;
    return (unsigned)ux | ((unsigned)uy << 16);
}
__device__ __forceinline__ float bf2f(unsigned short u) {
    union { unsigned u; float f; } v; v.u = ((unsigned)u) << 16; return v.f;
}

#if __has_builtin(__builtin_amdgcn_exp2f)
#define EXP2(x) __builtin_amdgcn_exp2f(x)
#else
#define EXP2(x) exp2f(x)
#endif

#define GLL(g, l) __builtin_amdgcn_global_load_lds( \
    (__attribute__((address_space(1))) void*)(g), \
    (__attribute__((address_space(3))) void*)(l), 16, 0, 0)

#define CS 0.18033688011112042f   /* 0.125 * log2(e) */

// ---------------------------------------------------------------------------
// 1. Convert the four 512x512 fp32 weight matrices to bf16 (concatenated).
// ---------------------------------------------------------------------------
__global__ __launch_bounds__(256) void convert_w(
    const float* __restrict__ wq, const float* __restrict__ wk,
    const float* __restrict__ wv, const float* __restrict__ wo,
    unsigned short* __restrict__ out)
{
    int i = blockIdx.x * 256 + threadIdx.x;
    const float* src = (i < 262144) ? wq : (i < 524288) ? wk : (i < 786432) ? wv : wo;
    out[i] = f2bf(src[i & 262143]);
}

// ---------------------------------------------------------------------------
// 2a. GroupNorm stats: grid (4 quarters, 64 b*g); partials -> part[(bg*4+q)*2]
// ---------------------------------------------------------------------------
__global__ __launch_bounds__(256) void gn_stats(
    const float* __restrict__ x, float* __restrict__ part)
{
    const int q = blockIdx.x, bg = blockIdx.y;
    const f4* xv = (const f4*)(x + (size_t)bg * 65536 + q * 16384);
    float s = 0.f, sq = 0.f;
    for (int i = threadIdx.x; i < 4096; i += 256) {
        f4 v = xv[i];
        s  += v.x + v.y + v.z + v.w;
        sq += v.x * v.x + v.y * v.y + v.z * v.z + v.w * v.w;
    }
    #pragma unroll
    for (int off = 32; off > 0; off >>= 1) {
        s  += __shfl_xor(s, off, 64);
        sq += __shfl_xor(sq, off, 64);
    }
    __shared__ float red[8];
    const int w = threadIdx.x >> 6, lane = threadIdx.x & 63;
    if (lane == 0) { red[w] = s; red[4 + w] = sq; }
    __syncthreads();
    if (threadIdx.x == 0) {
        part[(bg * 4 + q) * 2]     = red[0] + red[1] + red[2] + red[3];
        part[(bg * 4 + q) * 2 + 1] = red[4] + red[5] + red[6] + red[7];
    }
}

// ---------------------------------------------------------------------------
// 2b. GroupNorm apply -> h bf16 in [B*N, C] layout.
// ---------------------------------------------------------------------------
__global__ __launch_bounds__(256) void gn_apply(
    const float* __restrict__ x, const float* __restrict__ gamma,
    const float* __restrict__ beta, const float* __restrict__ part,
    unsigned short* __restrict__ h)
{
    const int q = blockIdx.x, bg = blockIdx.y;
    const int b = bg >> 5, g = bg & 31;
    float s = 0.f, sq = 0.f;
    #pragma unroll
    for (int j = 0; j < 4; ++j) {
        s  += part[(bg * 4 + j) * 2];
        sq += part[(bg * 4 + j) * 2 + 1];
    }
    const float mean = s * (1.f / 65536.f);
    const float rstd = rsqrtf(sq * (1.f / 65536.f) - mean * mean + 1e-5f);

    float gm[16], bt[16];
    #pragma unroll
    for (int c = 0; c < 16; ++c) {
        gm[c] = gamma[g * 16 + c] * rstd;
        bt[c] = beta[g * 16 + c];
    }
    const float* xg = x + (size_t)bg * 65536;
    const int n0 = q * 1024 + threadIdx.x * 4;
    float val[16][4];
    #pragma unroll
    for (int c = 0; c < 16; ++c) {
        f4 v = *(const f4*)&xg[(size_t)c * 4096 + n0];
        val[c][0] = (v.x - mean) * gm[c] + bt[c];
        val[c][1] = (v.y - mean) * gm[c] + bt[c];
        val[c][2] = (v.z - mean) * gm[c] + bt[c];
        val[c][3] = (v.w - mean) * gm[c] + bt[c];
    }
    #pragma unroll
    for (int nn = 0; nn < 4; ++nn) {
        ushort8 v0, v1;
        #pragma unroll
        for (int c = 0; c < 8; ++c)  v0[c]     = f2bf(val[c][nn]);
        #pragma unroll
        for (int c = 8; c < 16; ++c) v1[c - 8] = f2bf(val[c][nn]);
        unsigned short* dst = h + ((size_t)(b * 4096 + n0 + nn)) * 512 + g * 16;
        *(ushort8*)dst = v0;
        *(ushort8*)(dst + 8) = v1;
    }
}

// ---------------------------------------------------------------------------
// 3. bf16 GEMM  C[i,j] = sum_k A[i,k]*Bt[j,k] (+bias, +epilogue)
//    MODE 0 (BM=128): fused QKV. Q cols -> qout (pre-scaled CS), K -> kout,
//                     V -> vt[bh][d][n] (fused transpose).
//    MODE 1 (BM=64):  out fp32 transposed to [B,C,H,W] + residual, bias by i.
// ---------------------------------------------------------------------------
template <int MODE, int BM>
__global__ __launch_bounds__(256, 2) void gemm_bt(
    const unsigned short* __restrict__ A,   // [M,K] bf16
    const unsigned short* __restrict__ Bt,  // [N,K] bf16
    const float* __restrict__ bias0,
    const float* __restrict__ bias1,
    const float* __restrict__ bias2,
    const float* __restrict__ resid,
    void* __restrict__ outp,                // MODE0: qout / MODE1: fp32 out
    unsigned short* __restrict__ kout,
    unsigned short* __restrict__ vtout,
    int M, int N, int K)
{
    constexpr int MT = BM / 32;             // m-frags per wave
    __shared__ __attribute__((aligned(16))) unsigned short As[BM * 32];
    __shared__ __attribute__((aligned(16))) unsigned short Bs[128 * 32];
    const int t = threadIdx.x;
    const int w = t >> 6, lane = t & 63;
    const int l15 = lane & 15, l4 = lane >> 4;
    const int bm = blockIdx.y, bn = blockIdx.x;
    const int wm = (w >> 1) * (BM / 2), wn = (w & 1) * 64;

    f32x4 acc[MT][4] = {};

    const int srow = t >> 2;
    const int sc8  = (t & 3) * 8;

    const unsigned short* gA0 = A  + (size_t)(bm * BM + srow) * K + sc8;
    const unsigned short* gB0 = Bt + (size_t)(bn * 128 + srow) * K + sc8;
    const unsigned short* gB1 = gB0 + (size_t)64 * K;
    unsigned short* lA0 = &As[w * 512];
    unsigned short* lB0 = &Bs[w * 512];
    unsigned short* lB1 = &Bs[2048 + w * 512];

    for (int k0 = 0; k0 < K; k0 += 32) {
        __syncthreads();
        GLL(gA0 + k0, lA0);
        if (BM == 128) GLL(gA0 + (size_t)64 * K + k0, &As[2048 + w * 512]);
        GLL(gB0 + k0, lB0);
        GLL(gB1 + k0, lB1);
        __syncthreads();

        bf16x8 af[MT], bfr[4];
        #pragma unroll
        for (int mt = 0; mt < MT; ++mt)
            af[mt] = *(const bf16x8*)&As[(wm + mt * 16 + l15) * 32 + l4 * 8];
        #pragma unroll
        for (int nt = 0; nt < 4; ++nt)
            bfr[nt] = *(const bf16x8*)&Bs[(wn + nt * 16 + l15) * 32 + l4 * 8];
        #pragma unroll
        for (int mt = 0; mt < MT; ++mt)
            #pragma unroll
            for (int nt = 0; nt < 4; ++nt)
                acc[mt][nt] = __builtin_amdgcn_mfma_f32_16x16x32_bf16(
                    af[mt], bfr[nt], acc[mt][nt], 0, 0, 0);
    }

    if (MODE == 0) {
        unsigned short* qout = (unsigned short*)outp;
        #pragma unroll
        for (int nt = 0; nt < 4; ++nt) {
            int col = bn * 128 + wn + nt * 16 + l15;
            const float* bp = (col < 512) ? bias0 : (col < 1024) ? bias1 : bias2;
            float bv = bp[col & 511];
            if (col < 1024) {                   // Q (pre-scaled) / K compact
                unsigned short* dst = (col < 512) ? qout : kout;
                int cc = col & 511;
                float sc = (col < 512) ? CS : 1.0f;
                #pragma unroll
                for (int mt = 0; mt < MT; ++mt)
                    #pragma unroll
                    for (int r = 0; r < 4; ++r) {
                        int row = bm * BM + wm + mt * 16 + l4 * 4 + r;
                        dst[(size_t)row * 512 + cc] = f2bf((acc[mt][nt][r] + bv) * sc);
                    }
            } else {                            // V -> vt[bh][d][n] directly
                int hd = col - 1024;            // h*64 + d
                #pragma unroll
                for (int mt = 0; mt < MT; ++mt) {
                    int m = bm * BM + wm + mt * 16 + l4 * 4;   // n base (r=0)
                    int bb = m >> 12, n = m & 4095;
                    unsigned u0 = pk2bf(acc[mt][nt][0] + bv, acc[mt][nt][1] + bv);
                    unsigned u1 = pk2bf(acc[mt][nt][2] + bv, acc[mt][nt][3] + bv);
                    unsigned short* dst = vtout +
                        ((size_t)(bb * 8 + (hd >> 6)) * 64 + (hd & 63)) * 4096 + n;
                    *(u32x2*)dst = (u32x2){u0, u1};
                }
            }
        }
    } else {
        float* outF = (float*)outp;
        #pragma unroll
        for (int mt = 0; mt < MT; ++mt)
            #pragma unroll
            for (int nt = 0; nt < 4; ++nt)
                #pragma unroll
                for (int r = 0; r < 4; ++r) {
                    int c = bm * BM + wm + mt * 16 + l4 * 4 + r;
                    int m = bn * 128 + wn + nt * 16 + l15;
                    int b = m >> 12, n = m & 4095;
                    size_t idx = ((size_t)(b * 512 + c)) * 4096 + n;
                    outF[idx] = acc[mt][nt][r] + bias0[c] + resid[idx];
                }
    }
}

// ---------------------------------------------------------------------------
// 4. Flash attention, 32x32x16 MFMA, 64 q/wave, fixed-shift softmax,
//    2-way key split. Block = 4 waves x 64 q = 256 q of one (b,h), 2048 keys.
//    launch_bounds(256,2): ~184 regs, NO spill (R6/R7 proved 3 waves = spill).
//    KEY-PERMUTED K staging: LDS key-slot s holds logical key pi(s),
//    pi = [0-3, 8-11, 4-7, 12-15] per 16-block. Then S^T C-layout registers
//    hold exactly the PV B-operand's keys in register order -> sequential
//    pk2bf pack, NO permlane swaps. V and row-sums are permutation-invariant.
//    Emits UNNORMALIZED bf16 O-partials + fp32 l-partials; combine_o merges.
// ---------------------------------------------------------------------------
__global__ __launch_bounds__(256, 2) void attn_kernel(
    const unsigned short* __restrict__ qb, const unsigned short* __restrict__ kb,
    const unsigned short* __restrict__ vt,
    unsigned short* __restrict__ opart, float* __restrict__ lbuf)
{
    __shared__ __attribute__((aligned(16))) unsigned short Ks[64][72];
    __shared__ __attribute__((aligned(16))) unsigned short Vts[64][72];

    const int bh = blockIdx.y, b = bh >> 3, h = bh & 7;
    const int qbase = blockIdx.x * 256;
    const int s = blockIdx.z, ks0 = s * 2048;
    const int t = threadIdx.x, w = t >> 6, lane = t & 63;
    const int l31 = lane & 31, h5 = lane >> 5;

    const unsigned short* Qg = qb + ((size_t)(b * 4096 + qbase + w * 64)) * 512 + h * 64;
    const unsigned short* Kg = kb + ((size_t)(b * 4096 + ks0)) * 512 + h * 64;
    const unsigned short* Vg = vt + ((size_t)bh) * 64 * 4096 + ks0;

    // Q fragments (B-operand, persistent): q=qt*32+l31, d=kc*16+h5*8+j
    bf16x8 qf[2][4];
    #pragma unroll
    for (int qt = 0; qt < 2; ++qt)
        #pragma unroll
        for (int kc = 0; kc < 4; ++kc)
            qf[qt][kc] = *(const bf16x8*)(Qg + (size_t)(qt * 32 + l31) * 512 + kc * 16 + h5 * 8);

    f32x16 Oacc[2][2] = {};      // [dt][qt], C-layout: col=q, row=d
    float li[2] = {0.f, 0.f};

    // staging: 256 threads x 32 B for each of K (8 KB) and V^T (8 KB)
    // K slot sr holds logical key pi(sr): pi swaps 4-groups 1<->2 per 16-block
    const int sr = t >> 2, sc = (t & 3) * 16;
    const int grp = (sr >> 2) & 3;
    const int srcrow = (grp == 1) ? sr + 4 : (grp == 2) ? sr - 4 : sr;
    const unsigned short* gK = Kg + (size_t)srcrow * 512 + sc;
    const unsigned short* gV = Vg + (size_t)sr * 4096 + sc;
    unsigned short* lK = &Ks[sr][sc];
    unsigned short* lV = &Vts[sr][sc];

    ushort8 kr[2], vr[2];
    kr[0] = *(const ushort8*)(gK);
    kr[1] = *(const ushort8*)(gK + 8);
    vr[0] = *(const ushort8*)(gV);
    vr[1] = *(const ushort8*)(gV + 8);

    for (int kt = 0; kt < 32; ++kt) {
        __syncthreads();
        *(ushort8*)(lK)     = kr[0];
        *(ushort8*)(lK + 8) = kr[1];
        *(ushort8*)(lV)     = vr[0];
        *(ushort8*)(lV + 8) = vr[1];
        __syncthreads();
        if (kt < 31) {   // prefetch next tile into registers
            const unsigned short* nk = gK + (size_t)(kt + 1) * 64 * 512;
            const unsigned short* nv = gV + (kt + 1) * 64;
            kr[0] = *(const ushort8*)(nk);
            kr[1] = *(const ushort8*)(nk + 8);
            vr[0] = *(const ushort8*)(nv);
            vr[1] = *(const ushort8*)(nv + 8);
        }

        // ---- per 32-key column tile: S -> softmax -> PV (St short-lived) ----
        #pragma unroll
        for (int ct = 0; ct < 2; ++ct) {
            f32x16 St0 = {}, St1 = {};
            #pragma unroll
            for (int kc = 0; kc < 4; ++kc) {
                bf16x8 kf = *(const bf16x8*)&Ks[ct * 32 + l31][kc * 16 + h5 * 8];
                St0 = __builtin_amdgcn_mfma_f32_32x32x16_bf16(kf, qf[0][kc], St0, 0, 0, 0);
                St1 = __builtin_amdgcn_mfma_f32_32x32x16_bf16(kf, qf[1][kc], St1, 0, 0, 0);
            }

            #pragma unroll
            for (int r = 0; r < 16; ++r) St0[r] = EXP2(St0[r]);
            #pragma unroll
            for (int r = 0; r < 16; ++r) St1[r] = EXP2(St1[r]);

            float a0 = 0.f, a1 = 0.f;
            #pragma unroll
            for (int r = 0; r < 16; ++r) { a0 += St0[r]; a1 += St1[r]; }
            li[0] += a0; li[1] += a1;

            // direct sequential pack: St reg order == B-operand key order (pi)
            union PU { unsigned u[4]; bf16x8 v; };
            PU pf0[2], pf1[2];
            #pragma unroll
            for (int kkl = 0; kkl < 2; ++kkl)
                #pragma unroll
                for (int i = 0; i < 4; ++i) {
                    pf0[kkl].u[i] = pk2bf(St0[kkl * 8 + 2 * i], St0[kkl * 8 + 2 * i + 1]);
                    pf1[kkl].u[i] = pk2bf(St1[kkl * 8 + 2 * i], St1[kkl * 8 + 2 * i + 1]);
                }

            #pragma unroll
            for (int kkl = 0; kkl < 2; ++kkl)
                #pragma unroll
                for (int dt = 0; dt < 2; ++dt) {
                    bf16x8 vf = *(const bf16x8*)&Vts[dt * 32 + l31][(ct * 2 + kkl) * 16 + h5 * 8];
                    Oacc[dt][0] = __builtin_amdgcn_mfma_f32_32x32x16_bf16(vf, pf0[kkl].v, Oacc[dt][0], 0, 0, 0);
                    Oacc[dt][1] = __builtin_amdgcn_mfma_f32_32x32x16_bf16(vf, pf1[kkl].v, Oacc[dt][1], 0, 0, 0);
                }
        }
    }

    // ---- epilogue: UNNORMALIZED partials, direct dword stores (no LDS) ----
    #pragma unroll
    for (int qt = 0; qt < 2; ++qt) {
        float lf = li[qt] + __shfl_xor(li[qt], 32, 64);
        size_t qrow = ((size_t)s * 16 + bh) * 4096 + qbase + w * 64 + qt * 32 + l31;
        if (h5 == 0) lbuf[qrow] = lf;
        unsigned short* orow = opart + qrow * 64;
        #pragma unroll
        for (int dt = 0; dt < 2; ++dt)
            #pragma unroll
            for (int p = 0; p < 8; ++p) {
                int d = dt * 32 + 2 * (p & 1) + 8 * (p >> 1) + 4 * h5;
                unsigned u = pk2bf(Oacc[dt][qt][2 * p], Oacc[dt][qt][2 * p + 1]);
                *(unsigned*)(orow + d) = u;
            }
    }
}

// ---------------------------------------------------------------------------
// 5. Combine 2 key-split partials: O = sum(Os)/sum(ls) -> [B*N, C] bf16
// ---------------------------------------------------------------------------
__global__ __launch_bounds__(256) void combine_o(
    const unsigned short* __restrict__ opart, const float* __restrict__ lbuf,
    unsigned short* __restrict__ o)
{
    int gid = blockIdx.x * 256 + threadIdx.x;   // 524288 = 65536 rows x 8 chunks
    int row = gid >> 3, c8 = gid & 7;           // row = bh*4096 + q
    int bh = row >> 12, q = row & 4095;
    int b = bh >> 3, h = bh & 7;
    float inv = 1.f / (lbuf[row] + lbuf[65536 + row]);
    ushort8 o0 = *(const ushort8*)(opart + (size_t)row * 64 + c8 * 8);
    ushort8 o1 = *(const ushort8*)(opart + ((size_t)65536 + row) * 64 + c8 * 8);
    ushort8 r;
    #pragma unroll
    for (int i = 0; i < 8; ++i)
        r[i] = f2bf((bf2f(o0[i]) + bf2f(o1[i])) * inv);
    *(ushort8*)(o + ((size_t)(b * 4096 + q)) * 512 + h * 64 + c8 * 8) = r;
}

// ---------------------------------------------------------------------------
// launch
// ---------------------------------------------------------------------------
extern "C" void kernel_launch(void* const* d_in, const int* in_sizes, int n_in,
                              void* d_out, int out_size, void* d_ws, size_t ws_size,
                              hipStream_t stream) {
    const float* x     = (const float*)d_in[0];
    const float* gamma = (const float*)d_in[1];
    const float* beta  = (const float*)d_in[2];
    const float* Wq    = (const float*)d_in[3];
    const float* bq    = (const float*)d_in[4];
    const float* Wk    = (const float*)d_in[5];
    const float* bk    = (const float*)d_in[6];
    const float* Wv    = (const float*)d_in[7];
    const float* bv    = (const float*)d_in[8];
    const float* Wo    = (const float*)d_in[9];
    const float* bo    = (const float*)d_in[10];
    float* out = (float*)d_out;

    char* ws = (char*)d_ws;
    const size_t MB = 1024 * 1024;
    // Overlay layout:
    //   @0  qbuf 8MB
    //   @8  kbuf 8MB   -> reused as Obuf by combine_o (kbuf dead post-attn)
    //   @16 vtb  8MB
    //   @24 h    8MB (GN out, dead after QKV GEMM) -> opart overlays it
    //   @24 opart 16MB ([24,40))
    //   @56 wb   2MB
    //   @58 gnpart 4KB
    //   @58.25 lbuf 512KB
    unsigned short* qbuf   = (unsigned short*)(ws);
    unsigned short* kbuf   = (unsigned short*)(ws + 8 * MB);
    unsigned short* obuf   = kbuf;
    unsigned short* vtb    = (unsigned short*)(ws + 16 * MB);
    unsigned short* h      = (unsigned short*)(ws + 24 * MB);
    unsigned short* opart  = (unsigned short*)(ws + 24 * MB);
    unsigned short* wb     = (unsigned short*)(ws + 56 * MB);
    float*          gnpart = (float*)(ws + 58 * MB);
    float*          lbuf   = (float*)(ws + 58 * MB + 256 * 1024);

    convert_w<<<dim3(4096), dim3(256), 0, stream>>>(Wq, Wk, Wv, Wo, wb);
    gn_stats<<<dim3(4, 64), dim3(256), 0, stream>>>(x, gnpart);
    gn_apply<<<dim3(4, 64), dim3(256), 0, stream>>>(x, gamma, beta, gnpart, h);

    // fused qkv: Q->qbuf (CS-scaled), K->kbuf, V->vtb (transposed)
    gemm_bt<0, 128><<<dim3(12, 64), dim3(256), 0, stream>>>(
        h, wb, bq, bk, bv, nullptr, qbuf, kbuf, vtb, 8192, 1536, 512);

    attn_kernel<<<dim3(16, 16, 2), dim3(256), 0, stream>>>(qbuf, kbuf, vtb, opart, lbuf);
    combine_o<<<dim3(2048), dim3(256), 0, stream>>>(opart, lbuf, obuf);

    // out[b,c,n] = x + (O @ Wo^T + bo)^T : C[c, m] with A=Wo, Bt=O, BM=64
    gemm_bt<1, 64><<<dim3(64, 8), dim3(256), 0, stream>>>(
        wb + 786432, obuf, bo, nullptr, nullptr, x, out, nullptr, nullptr, 512, 8192, 512);
}

// Round 9
// 224.812 us; speedup vs baseline: 2.9735x; 1.0078x over previous
//
#include <hip/hip_runtime.h>
#include <cstdint>
#include <cstddef>

typedef __bf16 bf16x8 __attribute__((ext_vector_type(8)));
typedef float f32x4 __attribute__((ext_vector_type(4)));
typedef float f32x2 __attribute__((ext_vector_type(2)));
typedef float f32x16 __attribute__((ext_vector_type(16)));
typedef unsigned short ushort8 __attribute__((ext_vector_type(8)));
typedef unsigned u32x2 __attribute__((ext_vector_type(2)));
typedef float f4 __attribute__((ext_vector_type(4)));

__device__ __forceinline__ unsigned short f2bf(float f) {
    __bf16 b = (__bf16)f;
    return *(unsigned short*)&b;
}
__device__ __forceinline__ unsigned pk2bf(float a, float b) {
#if __has_builtin(__builtin_amdgcn_cvt_pk_bf16_f32)
    typedef __bf16 bf16x2v __attribute__((ext_vector_type(2)));
    bf16x2v r = __builtin_amdgcn_cvt_pk_bf16_f32(a, b);
    return *(unsigned*)&r;
#else
    __bf16 x = (__bf16)a, y = (__bf16)b;
    unsigned short ux = *(unsigned short*)&x, uy = *(unsigned short*)&y;
    return (unsigned)ux | ((unsigned)uy << 16);
#endif
}
__device__ __forceinline__ float bf2f(unsigned short u) {
    union { unsigned u; float f; } v; v.u = ((unsigned)u) << 16; return v.f;
}

#if __has_builtin(__builtin_amdgcn_exp2f)
#define EXP2(x) __builtin_amdgcn_exp2f(x)
#else
#define EXP2(x) exp2f(x)
#endif

#define GLL(g, l) __builtin_amdgcn_global_load_lds( \
    (__attribute__((address_space(1))) void*)(g), \
    (__attribute__((address_space(3))) void*)(l), 16, 0, 0)

#define CS 0.18033688011112042f   /* 0.125 * log2(e) */

// ---------------------------------------------------------------------------
// 1. prep: grid-partitioned. Blocks 0..4095: convert the four 512x512 fp32
//    weight matrices to bf16. Blocks 4096..4351: GroupNorm partial stats.
// ---------------------------------------------------------------------------
__global__ __launch_bounds__(256) void prep(
    const float* __restrict__ wq, const float* __restrict__ wk,
    const float* __restrict__ wv, const float* __restrict__ wo,
    unsigned short* __restrict__ wb,
    const float* __restrict__ x, float* __restrict__ part)
{
    const int bid = blockIdx.x;
    if (bid < 4096) {
        int i = bid * 256 + threadIdx.x;
        const float* src = (i < 262144) ? wq : (i < 524288) ? wk : (i < 786432) ? wv : wo;
        wb[i] = f2bf(src[i & 262143]);
        return;
    }
    const int idx = bid - 4096;           // 256 = 64 bg x 4 quarters
    const int q = idx & 3, bg = idx >> 2;
    const f4* xv = (const f4*)(x + (size_t)bg * 65536 + q * 16384);
    float s = 0.f, sq = 0.f;
    for (int i = threadIdx.x; i < 4096; i += 256) {
        f4 v = xv[i];
        s  += v.x + v.y + v.z + v.w;
        sq += v.x * v.x + v.y * v.y + v.z * v.z + v.w * v.w;
    }
    #pragma unroll
    for (int off = 32; off > 0; off >>= 1) {
        s  += __shfl_xor(s, off, 64);
        sq += __shfl_xor(sq, off, 64);
    }
    __shared__ float red[8];
    const int w = threadIdx.x >> 6, lane = threadIdx.x & 63;
    if (lane == 0) { red[w] = s; red[4 + w] = sq; }
    __syncthreads();
    if (threadIdx.x == 0) {
        part[(bg * 4 + q) * 2]     = red[0] + red[1] + red[2] + red[3];
        part[(bg * 4 + q) * 2 + 1] = red[4] + red[5] + red[6] + red[7];
    }
}

// ---------------------------------------------------------------------------
// 2. GroupNorm apply -> h bf16 in [B*N, C] layout.
// ---------------------------------------------------------------------------
__global__ __launch_bounds__(256) void gn_apply(
    const float* __restrict__ x, const float* __restrict__ gamma,
    const float* __restrict__ beta, const float* __restrict__ part,
    unsigned short* __restrict__ h)
{
    const int q = blockIdx.x, bg = blockIdx.y;
    const int b = bg >> 5, g = bg & 31;
    float s = 0.f, sq = 0.f;
    #pragma unroll
    for (int j = 0; j < 4; ++j) {
        s  += part[(bg * 4 + j) * 2];
        sq += part[(bg * 4 + j) * 2 + 1];
    }
    const float mean = s * (1.f / 65536.f);
    const float rstd = rsqrtf(sq * (1.f / 65536.f) - mean * mean + 1e-5f);

    float gm[16], bt[16];
    #pragma unroll
    for (int c = 0; c < 16; ++c) {
        gm[c] = gamma[g * 16 + c] * rstd;
        bt[c] = beta[g * 16 + c];
    }
    const float* xg = x + (size_t)bg * 65536;
    const int n0 = q * 1024 + threadIdx.x * 4;
    float val[16][4];
    #pragma unroll
    for (int c = 0; c < 16; ++c) {
        f4 v = *(const f4*)&xg[(size_t)c * 4096 + n0];
        val[c][0] = (v.x - mean) * gm[c] + bt[c];
        val[c][1] = (v.y - mean) * gm[c] + bt[c];
        val[c][2] = (v.z - mean) * gm[c] + bt[c];
        val[c][3] = (v.w - mean) * gm[c] + bt[c];
    }
    #pragma unroll
    for (int nn = 0; nn < 4; ++nn) {
        ushort8 v0, v1;
        #pragma unroll
        for (int c = 0; c < 8; ++c)  v0[c]     = f2bf(val[c][nn]);
        #pragma unroll
        for (int c = 8; c < 16; ++c) v1[c - 8] = f2bf(val[c][nn]);
        unsigned short* dst = h + ((size_t)(b * 4096 + n0 + nn)) * 512 + g * 16;
        *(ushort8*)dst = v0;
        *(ushort8*)(dst + 8) = v1;
    }
}

// ---------------------------------------------------------------------------
// 3. bf16 GEMM  C[i,j] = sum_k A[i,k]*Bt[j,k] (+bias, +epilogue)
//    MODE 0 (BM=128): fused QKV. Q cols -> qout (pre-scaled CS), K -> kout,
//                     V -> vt[bh][d][n] (fused transpose).
//    MODE 1 (BM=64):  out fp32 transposed to [B,C,H,W] + residual, bias by i.
// ---------------------------------------------------------------------------
template <int MODE, int BM>
__global__ __launch_bounds__(256, 2) void gemm_bt(
    const unsigned short* __restrict__ A,   // [M,K] bf16
    const unsigned short* __restrict__ Bt,  // [N,K] bf16
    const float* __restrict__ bias0,
    const float* __restrict__ bias1,
    const float* __restrict__ bias2,
    const float* __restrict__ resid,
    void* __restrict__ outp,                // MODE0: qout / MODE1: fp32 out
    unsigned short* __restrict__ kout,
    unsigned short* __restrict__ vtout,
    int M, int N, int K)
{
    constexpr int MT = BM / 32;             // m-frags per wave
    __shared__ __attribute__((aligned(16))) unsigned short As[BM * 32];
    __shared__ __attribute__((aligned(16))) unsigned short Bs[128 * 32];
    const int t = threadIdx.x;
    const int w = t >> 6, lane = t & 63;
    const int l15 = lane & 15, l4 = lane >> 4;
    const int bm = blockIdx.y, bn = blockIdx.x;
    const int wm = (w >> 1) * (BM / 2), wn = (w & 1) * 64;

    f32x4 acc[MT][4] = {};

    const int srow = t >> 2;
    const int sc8  = (t & 3) * 8;

    const unsigned short* gA0 = A  + (size_t)(bm * BM + srow) * K + sc8;
    const unsigned short* gB0 = Bt + (size_t)(bn * 128 + srow) * K + sc8;
    const unsigned short* gB1 = gB0 + (size_t)64 * K;
    unsigned short* lA0 = &As[w * 512];
    unsigned short* lB0 = &Bs[w * 512];
    unsigned short* lB1 = &Bs[2048 + w * 512];

    for (int k0 = 0; k0 < K; k0 += 32) {
        __syncthreads();
        GLL(gA0 + k0, lA0);
        if (BM == 128) GLL(gA0 + (size_t)64 * K + k0, &As[2048 + w * 512]);
        GLL(gB0 + k0, lB0);
        GLL(gB1 + k0, lB1);
        __syncthreads();

        bf16x8 af[MT], bfr[4];
        #pragma unroll
        for (int mt = 0; mt < MT; ++mt)
            af[mt] = *(const bf16x8*)&As[(wm + mt * 16 + l15) * 32 + l4 * 8];
        #pragma unroll
        for (int nt = 0; nt < 4; ++nt)
            bfr[nt] = *(const bf16x8*)&Bs[(wn + nt * 16 + l15) * 32 + l4 * 8];
        #pragma unroll
        for (int mt = 0; mt < MT; ++mt)
            #pragma unroll
            for (int nt = 0; nt < 4; ++nt)
                acc[mt][nt] = __builtin_amdgcn_mfma_f32_16x16x32_bf16(
                    af[mt], bfr[nt], acc[mt][nt], 0, 0, 0);
    }

    if (MODE == 0) {
        unsigned short* qout = (unsigned short*)outp;
        #pragma unroll
        for (int nt = 0; nt < 4; ++nt) {
            int col = bn * 128 + wn + nt * 16 + l15;
            const float* bp = (col < 512) ? bias0 : (col < 1024) ? bias1 : bias2;
            float bv = bp[col & 511];
            if (col < 1024) {                   // Q (pre-scaled) / K compact
                unsigned short* dst = (col < 512) ? qout : kout;
                int cc = col & 511;
                float sc = (col < 512) ? CS : 1.0f;
                #pragma unroll
                for (int mt = 0; mt < MT; ++mt)
                    #pragma unroll
                    for (int r = 0; r < 4; ++r) {
                        int row = bm * BM + wm + mt * 16 + l4 * 4 + r;
                        dst[(size_t)row * 512 + cc] = f2bf((acc[mt][nt][r] + bv) * sc);
                    }
            } else {                            // V -> vt[bh][d][n] directly
                int hd = col - 1024;            // h*64 + d
                #pragma unroll
                for (int mt = 0; mt < MT; ++mt) {
                    int m = bm * BM + wm + mt * 16 + l4 * 4;   // n base (r=0)
                    int bb = m >> 12, n = m & 4095;
                    unsigned u0 = pk2bf(acc[mt][nt][0] + bv, acc[mt][nt][1] + bv);
                    unsigned u1 = pk2bf(acc[mt][nt][2] + bv, acc[mt][nt][3] + bv);
                    unsigned short* dst = vtout +
                        ((size_t)(bb * 8 + (hd >> 6)) * 64 + (hd & 63)) * 4096 + n;
                    *(u32x2*)dst = (u32x2){u0, u1};
                }
            }
        }
    } else {
        float* outF = (float*)outp;
        #pragma unroll
        for (int mt = 0; mt < MT; ++mt)
            #pragma unroll
            for (int nt = 0; nt < 4; ++nt)
                #pragma unroll
                for (int r = 0; r < 4; ++r) {
                    int c = bm * BM + wm + mt * 16 + l4 * 4 + r;
                    int m = bn * 128 + wn + nt * 16 + l15;
                    int b = m >> 12, n = m & 4095;
                    size_t idx = ((size_t)(b * 512 + c)) * 4096 + n;
                    outF[idx] = acc[mt][nt][r] + bias0[c] + resid[idx];
                }
    }
}

// ---------------------------------------------------------------------------
// 4. Flash attention, 32x32x16 MFMA, 64 q/wave, fixed-shift softmax,
//    2-way key split. Block = 4 waves x 64 q = 256 q of one (b,h), 2048 keys.
//    MONOLITHIC phases (R5's winning structure): 16-MFMA S burst -> softmax
//    for both q-tiles -> 16-MFMA PV burst. KEY-PERMUTED K staging (R8's
//    winning piece): LDS key-slot s holds logical key pi(s), pi = [0-3, 8-11,
//    4-7, 12-15] per 16-block, so S^T C-layout register order == PV B-operand
//    key order -> sequential pack, NO cross-lane ops. launch_bounds(256,2):
//    3-waves/SIMD caps spill (R6/R7).
//    Emits UNNORMALIZED bf16 O-partials + fp32 l-partials; combine_o merges.
// ---------------------------------------------------------------------------
__global__ __launch_bounds__(256, 2) void attn_kernel(
    const unsigned short* __restrict__ qb, const unsigned short* __restrict__ kb,
    const unsigned short* __restrict__ vt,
    unsigned short* __restrict__ opart, float* __restrict__ lbuf)
{
    __shared__ __attribute__((aligned(16))) unsigned short Ks[64][72];
    __shared__ __attribute__((aligned(16))) unsigned short Vts[64][72];

    const int bh = blockIdx.y, b = bh >> 3, h = bh & 7;
    const int qbase = blockIdx.x * 256;
    const int s = blockIdx.z, ks0 = s * 2048;
    const int t = threadIdx.x, w = t >> 6, lane = t & 63;
    const int l31 = lane & 31, h5 = lane >> 5;

    const unsigned short* Qg = qb + ((size_t)(b * 4096 + qbase + w * 64)) * 512 + h * 64;
    const unsigned short* Kg = kb + ((size_t)(b * 4096 + ks0)) * 512 + h * 64;
    const unsigned short* Vg = vt + ((size_t)bh) * 64 * 4096 + ks0;

    // Q fragments (B-operand, persistent): q=qt*32+l31, d=kc*16+h5*8+j
    bf16x8 qf[2][4];
    #pragma unroll
    for (int qt = 0; qt < 2; ++qt)
        #pragma unroll
        for (int kc = 0; kc < 4; ++kc)
            qf[qt][kc] = *(const bf16x8*)(Qg + (size_t)(qt * 32 + l31) * 512 + kc * 16 + h5 * 8);

    f32x16 Oacc[2][2] = {};      // [dt][qt], C-layout: col=q, row=d
    float li[2] = {0.f, 0.f};

    // staging: 256 threads x 32 B for each of K (8 KB) and V^T (8 KB)
    // K slot sr holds logical key pi(sr): pi swaps 4-groups 1<->2 per 16-block
    const int sr = t >> 2, sc = (t & 3) * 16;
    const int grp = (sr >> 2) & 3;
    const int srcrow = (grp == 1) ? sr + 4 : (grp == 2) ? sr - 4 : sr;
    const unsigned short* gK = Kg + (size_t)srcrow * 512 + sc;
    const unsigned short* gV = Vg + (size_t)sr * 4096 + sc;
    unsigned short* lK = &Ks[sr][sc];
    unsigned short* lV = &Vts[sr][sc];

    ushort8 kr[2], vr[2];
    kr[0] = *(const ushort8*)(gK);
    kr[1] = *(const ushort8*)(gK + 8);
    vr[0] = *(const ushort8*)(gV);
    vr[1] = *(const ushort8*)(gV + 8);

    for (int kt = 0; kt < 32; ++kt) {
        __syncthreads();
        *(ushort8*)(lK)     = kr[0];
        *(ushort8*)(lK + 8) = kr[1];
        *(ushort8*)(lV)     = vr[0];
        *(ushort8*)(lV + 8) = vr[1];
        __syncthreads();
        if (kt < 31) {   // prefetch next tile into registers
            const unsigned short* nk = gK + (size_t)(kt + 1) * 64 * 512;
            const unsigned short* nv = gV + (kt + 1) * 64;
            kr[0] = *(const ushort8*)(nk);
            kr[1] = *(const ushort8*)(nk + 8);
            vr[0] = *(const ushort8*)(nv);
            vr[1] = *(const ushort8*)(nv + 8);
        }

        // ---- S phase: 16-MFMA burst, St[qt][ct] (scale pre-folded in Q) ----
        f32x16 St[2][2] = {};
        #pragma unroll
        for (int ct = 0; ct < 2; ++ct)
            #pragma unroll
            for (int kc = 0; kc < 4; ++kc) {
                bf16x8 kf = *(const bf16x8*)&Ks[ct * 32 + l31][kc * 16 + h5 * 8];
                St[0][ct] = __builtin_amdgcn_mfma_f32_32x32x16_bf16(kf, qf[0][kc], St[0][ct], 0, 0, 0);
                St[1][ct] = __builtin_amdgcn_mfma_f32_32x32x16_bf16(kf, qf[1][kc], St[1][ct], 0, 0, 0);
            }

        // ---- softmax phase: exp2, paired sums, sequential pack (pi order) --
        union PU { unsigned u[4]; bf16x8 v; };
        PU pf[2][4];
        #pragma unroll
        for (int qt = 0; qt < 2; ++qt) {
            f32x2 a2 = {0.f, 0.f};
            #pragma unroll
            for (int ct = 0; ct < 2; ++ct) {
                #pragma unroll
                for (int r = 0; r < 16; ++r)
                    St[qt][ct][r] = EXP2(St[qt][ct][r]);
                #pragma unroll
                for (int r = 0; r < 8; ++r) {
                    f32x2 p = {St[qt][ct][2 * r], St[qt][ct][2 * r + 1]};
                    a2 += p;
                }
                #pragma unroll
                for (int kkl = 0; kkl < 2; ++kkl)
                    #pragma unroll
                    for (int i = 0; i < 4; ++i)
                        pf[qt][ct * 2 + kkl].u[i] =
                            pk2bf(St[qt][ct][kkl * 8 + 2 * i], St[qt][ct][kkl * 8 + 2 * i + 1]);
            }
            li[qt] += a2[0] + a2[1];
        }

        // ---- PV phase: 16-MFMA burst ----
        #pragma unroll
        for (int kkl = 0; kkl < 4; ++kkl)
            #pragma unroll
            for (int dt = 0; dt < 2; ++dt) {
                bf16x8 vf = *(const bf16x8*)&Vts[dt * 32 + l31][kkl * 16 + h5 * 8];
                Oacc[dt][0] = __builtin_amdgcn_mfma_f32_32x32x16_bf16(vf, pf[0][kkl].v, Oacc[dt][0], 0, 0, 0);
                Oacc[dt][1] = __builtin_amdgcn_mfma_f32_32x32x16_bf16(vf, pf[1][kkl].v, Oacc[dt][1], 0, 0, 0);
            }
    }

    // ---- epilogue: UNNORMALIZED partials, direct dword stores (no LDS) ----
    #pragma unroll
    for (int qt = 0; qt < 2; ++qt) {
        float lf = li[qt] + __shfl_xor(li[qt], 32, 64);
        size_t qrow = ((size_t)s * 16 + bh) * 4096 + qbase + w * 64 + qt * 32 + l31;
        if (h5 == 0) lbuf[qrow] = lf;
        unsigned short* orow = opart + qrow * 64;
        #pragma unroll
        for (int dt = 0; dt < 2; ++dt)
            #pragma unroll
            for (int p = 0; p < 8; ++p) {
                int d = dt * 32 + 2 * (p & 1) + 8 * (p >> 1) + 4 * h5;
                unsigned u = pk2bf(Oacc[dt][qt][2 * p], Oacc[dt][qt][2 * p + 1]);
                *(unsigned*)(orow + d) = u;
            }
    }
}

// ---------------------------------------------------------------------------
// 5. Combine 2 key-split partials: O = sum(Os)/sum(ls) -> [B*N, C] bf16
// ---------------------------------------------------------------------------
__global__ __launch_bounds__(256) void combine_o(
    const unsigned short* __restrict__ opart, const float* __restrict__ lbuf,
    unsigned short* __restrict__ o)
{
    int gid = blockIdx.x * 256 + threadIdx.x;   // 524288 = 65536 rows x 8 chunks
    int row = gid >> 3, c8 = gid & 7;           // row = bh*4096 + q
    int bh = row >> 12, q = row & 4095;
    int b = bh >> 3, h = bh & 7;
    float inv = 1.f / (lbuf[row] + lbuf[65536 + row]);
    ushort8 o0 = *(const ushort8*)(opart + (size_t)row * 64 + c8 * 8);
    ushort8 o1 = *(const ushort8*)(opart + ((size_t)65536 + row) * 64 + c8 * 8);
    ushort8 r;
    #pragma unroll
    for (int i = 0; i < 8; ++i)
        r[i] = f2bf((bf2f(o0[i]) + bf2f(o1[i])) * inv);
    *(ushort8*)(o + ((size_t)(b * 4096 + q)) * 512 + h * 64 + c8 * 8) = r;
}

// ---------------------------------------------------------------------------
// launch
// ---------------------------------------------------------------------------
extern "C" void kernel_launch(void* const* d_in, const int* in_sizes, int n_in,
                              void* d_out, int out_size, void* d_ws, size_t ws_size,
                              hipStream_t stream) {
    const float* x     = (const float*)d_in[0];
    const float* gamma = (const float*)d_in[1];
    const float* beta  = (const float*)d_in[2];
    const float* Wq    = (const float*)d_in[3];
    const float* bq    = (const float*)d_in[4];
    const float* Wk    = (const float*)d_in[5];
    const float* bk    = (const float*)d_in[6];
    const float* Wv    = (const float*)d_in[7];
    const float* bv    = (const float*)d_in[8];
    const float* Wo    = (const float*)d_in[9];
    const float* bo    = (const float*)d_in[10];
    float* out = (float*)d_out;

    char* ws = (char*)d_ws;
    const size_t MB = 1024 * 1024;
    // Overlay layout:
    //   @0  qbuf 8MB
    //   @8  kbuf 8MB   -> reused as Obuf by combine_o (kbuf dead post-attn)
    //   @16 vtb  8MB
    //   @24 h    8MB (GN out, dead after QKV GEMM) -> opart overlays it
    //   @24 opart 16MB ([24,40))
    //   @56 wb   2MB
    //   @58 gnpart 4KB
    //   @58.25 lbuf 512KB
    unsigned short* qbuf   = (unsigned short*)(ws);
    unsigned short* kbuf   = (unsigned short*)(ws + 8 * MB);
    unsigned short* obuf   = kbuf;
    unsigned short* vtb    = (unsigned short*)(ws + 16 * MB);
    unsigned short* h      = (unsigned short*)(ws + 24 * MB);
    unsigned short* opart  = (unsigned short*)(ws + 24 * MB);
    unsigned short* wb     = (unsigned short*)(ws + 56 * MB);
    float*          gnpart = (float*)(ws + 58 * MB);
    float*          lbuf   = (float*)(ws + 58 * MB + 256 * 1024);

    prep<<<dim3(4352), dim3(256), 0, stream>>>(Wq, Wk, Wv, Wo, wb, x, gnpart);
    gn_apply<<<dim3(4, 64), dim3(256), 0, stream>>>(x, gamma, beta, gnpart, h);

    // fused qkv: Q->qbuf (CS-scaled), K->kbuf, V->vtb (transposed)
    gemm_bt<0, 128><<<dim3(12, 64), dim3(256), 0, stream>>>(
        h, wb, bq, bk, bv, nullptr, qbuf, kbuf, vtb, 8192, 1536, 512);

    attn_kernel<<<dim3(16, 16, 2), dim3(256), 0, stream>>>(qbuf, kbuf, vtb, opart, lbuf);
    combine_o<<<dim3(2048), dim3(256), 0, stream>>>(opart, lbuf, obuf);

    // out[b,c,n] = x + (O @ Wo^T + bo)^T : C[c, m] with A=Wo, Bt=O, BM=64
    gemm_bt<1, 64><<<dim3(64, 8), dim3(256), 0, stream>>>(
        wb + 786432, obuf, bo, nullptr, nullptr, x, out, nullptr, nullptr, 512, 8192, 512);
}